// Round 8
// baseline (1004.493 us; speedup 1.0000x reference)
//
#include <hip/hip_runtime.h>

typedef _Float16 f16;
typedef _Float16 f16x8 __attribute__((ext_vector_type(8)));
typedef _Float16 f16x4 __attribute__((ext_vector_type(4)));
typedef float    f32x4 __attribute__((ext_vector_type(4)));

// Problem constants: B=32, T=128, L=512, D=256, M=4, VOCAB=32000, HOPS=3
// DTYPE: ALL float inputs/outputs are fp32.

__device__ __forceinline__ float frcp(float x){
  float r; asm("v_rcp_f32 %0, %1" : "=v"(r) : "v"(x)); return r;
}
__device__ __forceinline__ float fsig(float x){ return frcp(1.0f + __expf(-x)); }
__device__ __forceinline__ float ftanh(float x){ return 2.0f*frcp(1.0f + __expf(-2.0f*x)) - 1.0f; }

// ---------------------------------------------------------------------------
__global__ void k_zero(float* out){
  int i = blockIdx.x*256 + threadIdx.x;
  if (i < 24576) out[i] = 0.f;
}

// ---------------------------------------------------------------------------
// K0: merged weight-convert (blocks 0..767) + embed-bag (blocks 768..4863).
__global__ __launch_bounds__(256) void k_prep(const float* __restrict__ s0,
                                              const float* __restrict__ s1,
                                              const float* __restrict__ s2,
                                              const float* __restrict__ s3,
                                              const float* __restrict__ s4,
                                              f16* __restrict__ d0, f16* __restrict__ d1,
                                              f16* __restrict__ d2, f16* __restrict__ d3,
                                              f16* __restrict__ d4,
                                              const int* __restrict__ conv,
                                              const float* __restrict__ tbl,
                                              f16* __restrict__ emb){
  int bid = blockIdx.x;
  if (bid < 768){
    int i = bid*256 + threadIdx.x;               // < 196608
    d0[i] = (f16)s0[i];                          // Wih_f  [768*256]
    d1[i] = (f16)s1[i];                          // Wih_b
    d2[i] = (f16)s2[i];                          // Whh_f
    d3[i] = (f16)s3[i];                          // Whh_b
    if (i < 131072) d4[i] = (f16)s4[i];          // W_w    [256*512]
    return;
  }
  int bt = bid - 768, d = threadIdx.x;           // embed-bag
  const int* ix = conv + (size_t)bt*4;
  float s = 0.f;
#pragma unroll
  for (int m = 0; m < 4; ++m) s += tbl[(size_t)ix[m]*256 + d];
  emb[(size_t)bt*256 + d] = (f16)s;
}

// ---------------------------------------------------------------------------
// K2: both directions in one launch: rev = blockIdx>>6, tile = blockIdx&63.
__global__ __launch_bounds__(256) void k_gx2(const f16* __restrict__ emb,
                                             const f16* __restrict__ wf,
                                             const f16* __restrict__ wb,
                                             const float* __restrict__ bih_f,
                                             const float* __restrict__ bhh_f,
                                             const float* __restrict__ bih_b,
                                             const float* __restrict__ bhh_b,
                                             f16* __restrict__ gx_f,
                                             f16* __restrict__ gx_b){
  int rev = blockIdx.x >> 6, blk = blockIdx.x & 63;
  const f16* W16 = rev ? wb : wf;
  const float* bih = rev ? bih_b : bih_f;
  const float* bhh = rev ? bhh_b : bhh_f;
  f16* gx = rev ? gx_b : gx_f;

  int lane = threadIdx.x & 63, wv = threadIdx.x >> 6;
  int l16 = lane & 15, l4 = lane >> 4;
  int mrow = blk*64 + wv*16;
  int m = mrow + l16;
  int t = m >> 5, b = m & 31;
  int tsrc = rev ? (127 - t) : t;
  const f16* arow = emb + (size_t)(b*128 + tsrc)*256;
  f16x8 af[8];
#pragma unroll
  for (int kt = 0; kt < 8; ++kt) af[kt] = *(const f16x8*)(arow + kt*32 + l4*8);

  for (int nt = 0; nt < 48; ++nt){
    int n = nt*16 + l16;
    const f16* brow = W16 + (size_t)n*256;   // B[k][n] = Wih[n][k]
    f32x4 acc = {0.f,0.f,0.f,0.f};
#pragma unroll
    for (int kt = 0; kt < 8; ++kt){
      f16x8 bf = *(const f16x8*)(brow + kt*32 + l4*8);
      acc = __builtin_amdgcn_mfma_f32_16x16x32_f16(af[kt], bf, acc, 0, 0, 0);
    }
    float bias = bih[n] + (n < 512 ? bhh[n] : 0.f);
#pragma unroll
    for (int r = 0; r < 4; ++r){
      int m2 = mrow + l4*4 + r;
      gx[(size_t)m2*768 + n] = (f16)(acc[r] + bias);
    }
  }
}

// ---------------------------------------------------------------------------
// K3: GRU (blocks 0-3, proven 344-us body) + CONCURRENT bagT gathers
// (blocks 4..4+64*ntab) on the ~252 idle CUs. (r7: verified — grumega 360 us,
// only +16 us vs pure GRU; all 4 tables gathered inside the window.)
__global__ __launch_bounds__(512, 1) void k_grumega(const f16* __restrict__ gx_f,
                                                    const f16* __restrict__ gx_b,
                                                    const f16* __restrict__ whhf16,
                                                    const f16* __restrict__ whhb16,
                                                    const float* __restrict__ bhh_f,
                                                    const float* __restrict__ bhh_b,
                                                    f16* __restrict__ Abuf,
                                                    const int* __restrict__ src,
                                                    const float* __restrict__ Ct,
                                                    f16* __restrict__ bagT,
                                                    int tab0, int tab1, int tab2, int tab3){
  int bid = blockIdx.x;
  if (bid >= 4){
    int gi = bid - 4;
    int slot = gi >> 6;
    int tab = slot == 0 ? tab0 : slot == 1 ? tab1 : slot == 2 ? tab2 : tab3;
    const float* tbl = Ct + (size_t)tab * 32000 * 256;
    f16* dst = bagT + (size_t)slot * 4194304;       // 16384*256 f16
    int tid = threadIdx.x;
    int d = tid & 255, half = tid >> 8;
    int base = (gi & 63) * 256;
#pragma unroll 2
    for (int it = 0; it < 128; ++it){
      int task = base + it*2 + half;                // b*512 + l
      int4 ix = *(const int4*)(src + (size_t)task*4);
      float s = tbl[(size_t)ix.x*256 + d] + tbl[(size_t)ix.y*256 + d]
              + tbl[(size_t)ix.z*256 + d] + tbl[(size_t)ix.w*256 + d];
      dst[(size_t)task*256 + d] = (f16)s;
    }
    return;
  }

  // ---- GRU block (verbatim proven body) ----
  int dir = bid >> 1, grp = bid & 1, b0 = grp*16;
  const f16*   gx  = dir ? gx_b   : gx_f;
  const f16*   Whh = dir ? whhb16 : whhf16;
  const float* bhh = dir ? bhh_b  : bhh_f;

  int tid = threadIdx.x, lane = tid & 63, wv = tid >> 6;
  int l16 = lane & 15, l4 = lane >> 4;

  __shared__ __align__(16) f16   a16[2][16][264];
  __shared__ __align__(16) float bhnL[256];
  for (int i = tid; i < (16*264*2)/4; i += 512) ((unsigned*)&a16[0][0][0])[i] = 0u;
  if (tid < 256) bhnL[tid] = bhh[512 + tid];

  f16x8 aW[2][3][8];
#pragma unroll
  for (int q = 0; q < 2; ++q){
    int Q = 2*wv + q;
#pragma unroll
    for (int g = 0; g < 3; ++g){
      const f16* wrow = Whh + (size_t)(g*256 + Q*16 + l16)*256;
#pragma unroll
      for (int kt = 0; kt < 8; ++kt) aW[q][g][kt] = *(const f16x8*)(wrow + kt*32 + l4*8);
    }
  }

  const f16* gp = gx + (size_t)(b0 + l16)*768;
  f16* ap  = Abuf + (size_t)(b0 + l16)*128*512 + dir*256 + (size_t)(dir ? 127 : 0)*512;
  int  astep = dir ? -512 : 512;
  f16* app = ap;

  const int d00 = (2*wv    )*16 + l4*4;
  const int d01 = (2*wv + 1)*16 + l4*4;

  f16x4 pend[2];
  pend[0] = (f16x4){(f16)0.f,(f16)0.f,(f16)0.f,(f16)0.f};
  pend[1] = (f16x4){(f16)0.f,(f16)0.f,(f16)0.f,(f16)0.f};

  __syncthreads();

#pragma unroll 1
  for (int t = 0; t < 128; ++t){
    if (t){
      *(f16x4*)(app + d00) = pend[0];
      *(f16x4*)(app + d01) = pend[1];
    }
    f16x4 xg[2][3];
#pragma unroll
    for (int q = 0; q < 2; ++q)
#pragma unroll
      for (int g = 0; g < 3; ++g)
        xg[q][g] = *(const f16x4*)(gp + g*256 + (2*wv+q)*16 + l4*4);

    const f16* rb = &a16[t & 1][l16][l4*8];

    f32x4 accr[2], accz[2];
#pragma unroll
    for (int q = 0; q < 2; ++q){ accr[q] = (f32x4){0.f,0.f,0.f,0.f};
                                 accz[q] = (f32x4){0.f,0.f,0.f,0.f}; }
#pragma unroll
    for (int kt = 0; kt < 8; ++kt){
      f16x8 bf = *(const f16x8*)(rb + kt*32);
#pragma unroll
      for (int q = 0; q < 2; ++q){
        accr[q] = __builtin_amdgcn_mfma_f32_16x16x32_f16(aW[q][0][kt], bf, accr[q], 0, 0, 0);
        accz[q] = __builtin_amdgcn_mfma_f32_16x16x32_f16(aW[q][1][kt], bf, accz[q], 0, 0, 0);
      }
    }
    f32x4 accn[2];
#pragma unroll
    for (int q = 0; q < 2; ++q) accn[q] = (f32x4){0.f,0.f,0.f,0.f};
#pragma unroll
    for (int kt = 0; kt < 8; ++kt){
      f16x8 bf = *(const f16x8*)(rb + kt*32);
#pragma unroll
      for (int q = 0; q < 2; ++q)
        accn[q] = __builtin_amdgcn_mfma_f32_16x16x32_f16(aW[q][2][kt], bf, accn[q], 0, 0, 0);
    }
    float rr[2][4], zz[2][4];
#pragma unroll
    for (int q = 0; q < 2; ++q)
#pragma unroll
      for (int r = 0; r < 4; ++r){
        rr[q][r] = fsig((float)xg[q][0][r] + accr[q][r]);
        zz[q][r] = fsig((float)xg[q][1][r] + accz[q][r]);
      }
    int nxt = (t & 1) ^ 1;
#pragma unroll
    for (int q = 0; q < 2; ++q){
      int d0 = (2*wv+q)*16 + l4*4;
      float4 bh4 = *(const float4*)(&bhnL[d0]);
      f16x4 hold = pend[q];
      f16x4 o4;
#pragma unroll
      for (int r = 0; r < 4; ++r){
        float bh = (r==0)?bh4.x:(r==1)?bh4.y:(r==2)?bh4.z:bh4.w;
        float nn = ftanh((float)xg[q][2][r] + rr[q][r]*(accn[q][r] + bh));
        float h2 = nn + zz[q][r]*((float)hold[r] - nn);
        o4[r] = (f16)h2;
      }
      *(f16x4*)(&a16[nxt][l16][d0]) = o4;
      pend[q] = o4;
    }
    app = ap; ap += astep;
    gp += 24576;
    __syncthreads();
  }
  *(f16x4*)(app + d00) = pend[0];
  *(f16x4*)(app + d01) = pend[1];
}

// ---------------------------------------------------------------------------
// K4: merged rnnout (blocks 0..63) + hidden (blocks 64..71).
__global__ __launch_bounds__(256) void k_post(const f16* __restrict__ Abuf,
                                              const f16* __restrict__ Ww16,
                                              const float* __restrict__ Wb,
                                              float* __restrict__ rnn,
                                              float* __restrict__ hidden,
                                              float* __restrict__ u){
  int bid = blockIdx.x;
  int lane = threadIdx.x & 63, wv = threadIdx.x >> 6;
  int l16 = lane & 15, l4 = lane >> 4;
  if (bid < 64){
    int mrow = bid*64 + wv*16;
    const f16* arow = Abuf + (size_t)(mrow + l16)*512;
    f16x8 af[16];
#pragma unroll
    for (int kt = 0; kt < 16; ++kt) af[kt] = *(const f16x8*)(arow + kt*32 + l4*8);
    for (int nt = 0; nt < 16; ++nt){
      int n = nt*16 + l16;
      const f16* brow = Ww16 + (size_t)n*512;
      f32x4 acc = {0.f,0.f,0.f,0.f};
#pragma unroll
      for (int kt = 0; kt < 16; ++kt){
        f16x8 bf = *(const f16x8*)(brow + kt*32 + l4*8);
        acc = __builtin_amdgcn_mfma_f32_16x16x32_f16(af[kt], bf, acc, 0, 0, 0);
      }
      float bias = Wb[n];
#pragma unroll
      for (int r = 0; r < 4; ++r)
        rnn[(size_t)(mrow + l4*4 + r)*256 + n] = acc[r] + bias;
    }
    return;
  }
  // hidden/u
  int hb = bid - 64;
  int mt = wv & 1, nt = hb*2 + (wv >> 1);
  int b = mt*16 + l16;
  const f16* rowf = Abuf + ((size_t)b*128 + 127)*512;
  const f16* rowb = Abuf + ((size_t)b*128)*512;
  f16x8 af[16];
#pragma unroll
  for (int kt = 0; kt < 16; ++kt){
    int k = kt*32 + l4*8;
    af[kt] = *(const f16x8*)((k < 256 ? rowf : rowb) + k);
  }
  int n = nt*16 + l16;
  const f16* brow = Ww16 + (size_t)n*512;
  f32x4 acc = {0.f,0.f,0.f,0.f};
#pragma unroll
  for (int kt = 0; kt < 16; ++kt){
    f16x8 bf = *(const f16x8*)(brow + kt*32 + l4*8);
    acc = __builtin_amdgcn_mfma_f32_16x16x32_f16(af[kt], bf, acc, 0, 0, 0);
  }
  float bias = Wb[n];
#pragma unroll
  for (int r = 0; r < 4; ++r){
    int bo = mt*16 + l4*4 + r;
    float v = acc[r] + bias;
    hidden[(size_t)bo*256 + n] = v;
    u[(size_t)bo*256 + n] = v;
  }
}

// ---------------------------------------------------------------------------
// K6: FUSED hop (r8). One block per batch element b; 512 threads.
// Requires precomputed raw bags for tables hop and hop+1 (ntab==4 path).
//   phase 1: logits[l=tid] = (bagA[b,l] (+rnn[rel]) ) . u[b]   (u in LDS)
//   phase 2: block-wide softmax (no global logits buffer)
//   phase 3: u[b][d] += sum_l pr[l]*(bagC[b,l][d] (+rnn)), NO atomics (sole owner)
//   last hop: also global_pointer = sigmoid(logits) and encoded = relu(proj)
__global__ __launch_bounds__(512) void k_hop(const int* __restrict__ kbl,
                                             const int* __restrict__ cvl,
                                             const f16* __restrict__ bagA,
                                             const f16* __restrict__ bagC,
                                             const float* __restrict__ rnn,
                                             float* __restrict__ u,
                                             float* __restrict__ gp_out, int last,
                                             const float* __restrict__ hidden,
                                             const float* __restrict__ pw,
                                             const float* __restrict__ pb,
                                             float* __restrict__ enc_out){
  int b = blockIdx.x, tid = threadIdx.x;
  int lane = tid & 63, wvi = tid >> 6;
  __shared__ float uL[256];
  __shared__ float pr[512];
  __shared__ float redm[8], reds[8];
  __shared__ float bcast;
  __shared__ float part[2][256];

  if (tid < 256) uL[tid] = u[(size_t)b*256 + tid];
  __syncthreads();

  int kb = kbl[b], cl = cvl[b];

  // ---- phase 1: one logit per thread ----
  const f16* brow = bagA + ((size_t)b*512 + tid)*256;
  int rel = tid - kb;
  bool inr = (rel >= 0 && rel < cl);
  int rc = rel < 127 ? rel : 127;
  const float* rrow = rnn + ((size_t)b*128 + (inr ? rc : 0))*256;
  float dot = 0.f;
  if (inr){
    for (int k = 0; k < 256; k += 8){
      f16x8 bv = *(const f16x8*)(brow + k);
      float4 r0 = *(const float4*)(rrow + k);
      float4 r1 = *(const float4*)(rrow + k + 4);
      dot += ((float)bv[0]+r0.x)*uL[k+0] + ((float)bv[1]+r0.y)*uL[k+1]
           + ((float)bv[2]+r0.z)*uL[k+2] + ((float)bv[3]+r0.w)*uL[k+3]
           + ((float)bv[4]+r1.x)*uL[k+4] + ((float)bv[5]+r1.y)*uL[k+5]
           + ((float)bv[6]+r1.z)*uL[k+6] + ((float)bv[7]+r1.w)*uL[k+7];
    }
  } else {
    for (int k = 0; k < 256; k += 8){
      f16x8 bv = *(const f16x8*)(brow + k);
      dot += (float)bv[0]*uL[k+0] + (float)bv[1]*uL[k+1]
           + (float)bv[2]*uL[k+2] + (float)bv[3]*uL[k+3]
           + (float)bv[4]*uL[k+4] + (float)bv[5]*uL[k+5]
           + (float)bv[6]*uL[k+6] + (float)bv[7]*uL[k+7];
    }
  }
  if (last) gp_out[(size_t)b*512 + tid] = fsig(dot);

  // ---- phase 2: softmax over 512 ----
  float m = dot;
#pragma unroll
  for (int off = 32; off >= 1; off >>= 1) m = fmaxf(m, __shfl_down(m, off));
  if (lane == 0) redm[wvi] = m;
  __syncthreads();
  if (tid == 0){
    float mm = redm[0];
#pragma unroll
    for (int i = 1; i < 8; ++i) mm = fmaxf(mm, redm[i]);
    bcast = mm;
  }
  __syncthreads();
  float e = __expf(dot - bcast);
  float s = e;
#pragma unroll
  for (int off = 32; off >= 1; off >>= 1) s += __shfl_down(s, off);
  if (lane == 0) reds[wvi] = s;
  __syncthreads();
  float stot = reds[0]+reds[1]+reds[2]+reds[3]+reds[4]+reds[5]+reds[6]+reds[7];
  pr[tid] = e * frcp(stot);
  __syncthreads();

  // ---- phase 3: o_k, halves over l ----
  int d = tid & 255, hf = tid >> 8;
  const f16* cbase = bagC + ((size_t)b*512 + hf*256)*256 + d;
  const float* rbase = rnn + (size_t)b*128*256 + d;
  float acc = 0.f;
  for (int l = 0; l < 256; ++l){
    int gl = hf*256 + l;
    float bag = (float)cbase[(size_t)l*256];
    int r2 = gl - kb;
    if (r2 >= 0 && r2 < cl){
      int rc2 = r2 < 127 ? r2 : 127;
      bag += rbase[(size_t)rc2*256];
    }
    acc += pr[gl] * bag;
  }
  part[hf][d] = acc;
  __syncthreads();
  if (tid < 256){
    float un = uL[tid] + part[0][tid] + part[1][tid];
    u[(size_t)b*256 + tid] = un;
    uL[tid] = un;
  }
  __syncthreads();

  // ---- last hop: encoded = relu(concat(hidden, u_final) . proj^T + pb) ----
  if (last){
    __shared__ float hL[256];
    if (tid < 256) hL[tid] = hidden[(size_t)b*256 + tid];
    __syncthreads();
    const float* w = pw + (size_t)d*512 + hf*256;
    const float* xv = hf ? uL : hL;
    float sacc = 0.f;
    for (int k = 0; k < 256; k += 4){
      float4 wq = *(const float4*)(w + k);
      sacc += wq.x*xv[k] + wq.y*xv[k+1] + wq.z*xv[k+2] + wq.w*xv[k+3];
    }
    part[hf][d] = sacc;
    __syncthreads();
    if (tid < 256)
      enc_out[(size_t)b*256 + tid] = fmaxf(part[0][tid] + part[1][tid] + pb[tid], 0.f);
  }
}

// ---------------------------------------------------------------------------
// Fallback hop kernels (ntab < 4 path) — unchanged from r7.
__global__ __launch_bounds__(256) void k_logits(const int* __restrict__ src,
                                                const int* __restrict__ kbl,
                                                const int* __restrict__ cvl,
                                                const float* __restrict__ tblA,
                                                const float* __restrict__ rnn,
                                                const float* __restrict__ u,
                                                float* __restrict__ logits,
                                                const f16* __restrict__ bag){
  int b = blockIdx.x >> 5, chunk = blockIdx.x & 31;
  int lane = threadIdx.x & 63, wv = threadIdx.x >> 6;
  int kb = kbl[b], cl = cvl[b];
  float4 uv = *(const float4*)(u + b*256 + lane*4);
#pragma unroll
  for (int i = 0; i < 4; ++i){
    int l = chunk*16 + wv*4 + i;
    float b0, b1, b2, b3;
    if (bag){
      f16x4 bv = *(const f16x4*)(bag + ((size_t)b*512 + l)*256 + lane*4);
      b0 = (float)bv[0]; b1 = (float)bv[1]; b2 = (float)bv[2]; b3 = (float)bv[3];
    } else {
      const int* sp = src + ((size_t)b*512 + l)*4;
      b0 = b1 = b2 = b3 = 0.f;
#pragma unroll
      for (int m = 0; m < 4; ++m){
        float4 wq = *(const float4*)(tblA + (size_t)sp[m]*256 + lane*4);
        b0 += wq.x; b1 += wq.y; b2 += wq.z; b3 += wq.w;
      }
    }
    int rel = l - kb;
    if (rel >= 0 && rel < cl){
      int rc = rel < 127 ? rel : 127;
      float4 rv = *(const float4*)(rnn + ((size_t)b*128 + rc)*256 + lane*4);
      b0 += rv.x; b1 += rv.y; b2 += rv.z; b3 += rv.w;
    }
    float p = b0*uv.x + b1*uv.y + b2*uv.z + b3*uv.w;
#pragma unroll
    for (int off = 32; off >= 1; off >>= 1) p += __shfl_down(p, off);
    if (lane == 0) logits[(size_t)b*512 + l] = p;
  }
}

__global__ __launch_bounds__(256) void k_okv(const int* __restrict__ src,
                                             const int* __restrict__ kbl,
                                             const int* __restrict__ cvl,
                                             const float* __restrict__ tblC,
                                             const float* __restrict__ rnn,
                                             const float* __restrict__ logits,
                                             float* __restrict__ u,
                                             float* __restrict__ gp_out, int write_gp,
                                             const f16* __restrict__ bagin,
                                             f16* __restrict__ bagout){
  int b = blockIdx.x >> 4, c = blockIdx.x & 15;
  int d = threadIdx.x, lane = d & 63, wv = d >> 6;
  __shared__ float red[4];
  __shared__ float bc;
  __shared__ float pr[512];
  __shared__ int   sidx[128];

  float v0 = logits[(size_t)b*512 + d];
  float v1 = logits[(size_t)b*512 + 256 + d];
  float m = fmaxf(v0, v1);
#pragma unroll
  for (int off = 32; off >= 1; off >>= 1) m = fmaxf(m, __shfl_down(m, off));
  if (lane == 0) red[wv] = m;
  __syncthreads();
  if (d == 0) bc = fmaxf(fmaxf(red[0], red[1]), fmaxf(red[2], red[3]));
  __syncthreads();
  float mx = bc;
  float e0 = __expf(v0 - mx), e1 = __expf(v1 - mx);
  float s = e0 + e1;
#pragma unroll
  for (int off = 32; off >= 1; off >>= 1) s += __shfl_down(s, off);
  __syncthreads();
  if (lane == 0) red[wv] = s;
  __syncthreads();
  if (d == 0) bc = red[0] + red[1] + red[2] + red[3];
  __syncthreads();
  float inv = 1.0f/bc;
  pr[d] = e0*inv; pr[256 + d] = e1*inv;
  if (d < 128) sidx[d] = src[(size_t)b*2048 + c*128 + d];
  if (write_gp && c == 0){
    gp_out[(size_t)b*512 + d]       = fsig(v0);
    gp_out[(size_t)b*512 + 256 + d] = fsig(v1);
  }
  __syncthreads();

  int kb = kbl[b], cl = cvl[b];
  float acc = 0.f;
  for (int l = 0; l < 32; ++l){
    float bag;
    if (bagin){
      bag = (float)bagin[((size_t)b*512 + c*32 + l)*256 + d];
    } else {
      const int* sp = sidx + l*4;
      bag = tblC[(size_t)sp[0]*256 + d] + tblC[(size_t)sp[1]*256 + d]
          + tblC[(size_t)sp[2]*256 + d] + tblC[(size_t)sp[3]*256 + d];
      if (bagout) bagout[((size_t)b*512 + c*32 + l)*256 + d] = (f16)bag;  // RAW
    }
    int rel = (c*32 + l) - kb;
    if (rel >= 0 && rel < cl){
      int rc = rel < 127 ? rel : 127;
      bag += rnn[((size_t)b*128 + rc)*256 + d];
    }
    acc += pr[c*32 + l] * bag;
  }
  atomicAdd(&u[(size_t)b*256 + d], acc);
}

// ---------------------------------------------------------------------------
// K7 (fallback only): encoded = relu(concat(hidden,u) . proj_w + pb)
__global__ void k_encoded(const float* __restrict__ hidden, const float* __restrict__ u,
                          const float* __restrict__ pw, const float* __restrict__ pb,
                          float* __restrict__ out){
  int b = blockIdx.x, d = threadIdx.x;
  const float* w = pw + (size_t)d*512;
  float s = pb[d];
  for (int k = 0; k < 256; ++k) s += hidden[b*256 + k] * w[k];
  for (int k = 0; k < 256; ++k) s += u[b*256 + k]      * w[256 + k];
  out[(size_t)b*256 + d] = fmaxf(s, 0.f);
}

// ---------------------------------------------------------------------------
extern "C" void kernel_launch(void* const* d_in, const int* in_sizes, int n_in,
                              void* d_out, int out_size, void* d_ws, size_t ws_size,
                              hipStream_t stream){
  (void)in_sizes; (void)n_in; (void)out_size;
  float* out = (float*)d_out;  // [0:16384) global_pointer, [16384:24576) encoded

  const size_t WS_NEEDED = 25034752;
  if (ws_size < WS_NEEDED){
    k_zero<<<96, 256, 0, stream>>>(out);
    return;
  }

  const int* conv  = (const int*)d_in[0];
  const int* src   = (const int*)d_in[1];
  const int* kbl   = (const int*)d_in[2];
  const int* cvl   = (const int*)d_in[3];
  const float* emb_ctx = (const float*)d_in[4];
  const float* Ct      = (const float*)d_in[5];
  const float* Wih_f = (const float*)d_in[6];
  const float* Whh_f = (const float*)d_in[7];
  const float* bih_f = (const float*)d_in[8];
  const float* bhh_f = (const float*)d_in[9];
  const float* Wih_b = (const float*)d_in[10];
  const float* Whh_b = (const float*)d_in[11];
  const float* bih_b = (const float*)d_in[12];
  const float* bhh_b = (const float*)d_in[13];
  const float* Ww = (const float*)d_in[14];
  const float* Wb = (const float*)d_in[15];
  const float* pw = (const float*)d_in[16];
  const float* pb = (const float*)d_in[17];

  char* ws = (char*)d_ws;
  f16*   emb    = (f16*)(ws);                  //  2,097,152  [4096][256] f16
  f16*   gx_f   = (f16*)(ws + 2097152);        //  6,291,456  [t*32+b][768] f16
  f16*   gx_b   = (f16*)(ws + 8388608);        //  6,291,456
  f16*   Abuf   = (f16*)(ws + 14680064);       //  4,194,304  [b*128+t][512] f16
  float* rnn    = (float*)(ws + 18874368);     //  4,194,304  [b*128+t][256] f32
  float* hidden = (float*)(ws + 23068672);     //     32,768
  float* u      = (float*)(ws + 23101440);     //     32,768
  float* logits = (float*)(ws + 23134208);     //     65,536
  f16*   wihf16 = (f16*)(ws + 23199744);       //    393,216  [768][256]
  f16*   wihb16 = (f16*)(ws + 23592960);       //    393,216
  f16*   whhf16 = (f16*)(ws + 23986176);       //    393,216
  f16*   whhb16 = (f16*)(ws + 24379392);       //    393,216
  f16*   ww16   = (f16*)(ws + 24772608);       //    262,144  [256][512]
                                               // end 25,034,752
  f16*   bagbuf = (f16*)(ws + 2097152);        // fallback raw-bag (gx region)
  f16*   bagT   = (f16*)(ws + WS_NEEDED);
  size_t avail  = ws_size - WS_NEEDED;
  int ntab = (int)(avail / 8388608); if (ntab > 4) ntab = 4;
  const int tabids[4] = {1, 2, 3, 0};
  const f16* bt[4] = {nullptr, nullptr, nullptr, nullptr};
  for (int s = 0; s < ntab; ++s) bt[tabids[s]] = bagT + (size_t)s*4194304;

  k_prep<<<4864, 256, 0, stream>>>(Wih_f, Wih_b, Whh_f, Whh_b, Ww,
                                   wihf16, wihb16, whhf16, whhb16, ww16,
                                   conv, emb_ctx, emb);
  k_gx2<<<128, 256, 0, stream>>>(emb, wihf16, wihb16,
                                 bih_f, bhh_f, bih_b, bhh_b, gx_f, gx_b);
  k_grumega<<<4 + 64*ntab, 512, 0, stream>>>(gx_f, gx_b, whhf16, whhb16,
                                             bhh_f, bhh_b, Abuf,
                                             src, Ct, bagT,
                                             tabids[0], tabids[1], tabids[2], tabids[3]);
  k_post<<<72, 256, 0, stream>>>(Abuf, ww16, Wb, rnn, hidden, u);

  if (ntab == 4){
    // fused hops: 1 block per b, no logits buffer, no atomics, encoded folded
    for (int hop = 0; hop < 3; ++hop)
      k_hop<<<32, 512, 0, stream>>>(kbl, cvl, bt[hop], bt[hop+1], rnn, u,
                                    out, hop == 2 ? 1 : 0,
                                    hidden, pw, pb, out + 16384);
  } else {
    for (int hop = 0; hop < 3; ++hop){
      const float* tA = Ct + (size_t)hop     * 32000 * 256;
      const float* tC = Ct + (size_t)(hop+1) * 32000 * 256;
      const f16* lbag = bt[hop] ? bt[hop] : (hop ? bagbuf : (const f16*)nullptr);
      const f16* obag = bt[hop + 1];
      f16* obout = (!obag && hop < 2) ? bagbuf : (f16*)nullptr;
      k_logits<<<1024, 256, 0, stream>>>(src, kbl, cvl, tA, rnn, u, logits, lbag);
      k_okv<<<512, 256, 0, stream>>>(src, kbl, cvl, tC, rnn, logits, u,
                                     out, hop == 2 ? 1 : 0, obag, obout);
    }
    k_encoded<<<32, 256, 0, stream>>>(hidden, u, pw, pb, out + 16384);
  }
}

// Round 9
// 911.953 us; speedup vs baseline: 1.1015x; 1.1015x over previous
//
#include <hip/hip_runtime.h>

typedef _Float16 f16;
typedef _Float16 f16x8 __attribute__((ext_vector_type(8)));
typedef _Float16 f16x4 __attribute__((ext_vector_type(4)));
typedef float    f32x4 __attribute__((ext_vector_type(4)));

// Problem constants: B=32, T=128, L=512, D=256, M=4, VOCAB=32000, HOPS=3
// DTYPE: ALL float inputs/outputs are fp32.

__device__ __forceinline__ float frcp(float x){
  float r; asm("v_rcp_f32 %0, %1" : "=v"(r) : "v"(x)); return r;
}
__device__ __forceinline__ float fsig(float x){ return frcp(1.0f + __expf(-x)); }
__device__ __forceinline__ float ftanh(float x){ return 2.0f*frcp(1.0f + __expf(-2.0f*x)) - 1.0f; }

// ---------------------------------------------------------------------------
__global__ void k_zero(float* out){
  int i = blockIdx.x*256 + threadIdx.x;
  if (i < 24576) out[i] = 0.f;
}

// ---------------------------------------------------------------------------
// K0: weight fp32->f16 only (embbag folded into k_gx2 in r9).
__global__ __launch_bounds__(256) void k_prep(const float* __restrict__ s0,
                                              const float* __restrict__ s1,
                                              const float* __restrict__ s2,
                                              const float* __restrict__ s3,
                                              const float* __restrict__ s4,
                                              f16* __restrict__ d0, f16* __restrict__ d1,
                                              f16* __restrict__ d2, f16* __restrict__ d3,
                                              f16* __restrict__ d4){
  int i = blockIdx.x*256 + threadIdx.x;          // grid covers 196608
  d0[i] = (f16)s0[i];                            // Wih_f  [768*256]
  d1[i] = (f16)s1[i];                            // Wih_b
  d2[i] = (f16)s2[i];                            // Whh_f
  d3[i] = (f16)s3[i];                            // Whh_b
  if (i < 131072) d4[i] = (f16)s4[i];            // W_w    [256*512]
}

// ---------------------------------------------------------------------------
// K2: gx for both dirs; r9: embed-bag gathered inline into padded LDS
// (emb_ctx fp32 rows summed -> embL), removing the separate embbag stage.
__global__ __launch_bounds__(256) void k_gx2(const int* __restrict__ conv,
                                             const float* __restrict__ etbl,
                                             const f16* __restrict__ wf,
                                             const f16* __restrict__ wb,
                                             const float* __restrict__ bih_f,
                                             const float* __restrict__ bhh_f,
                                             const float* __restrict__ bih_b,
                                             const float* __restrict__ bhh_b,
                                             f16* __restrict__ gx_f,
                                             f16* __restrict__ gx_b){
  int rev = blockIdx.x >> 6, blk = blockIdx.x & 63;
  const f16* W16 = rev ? wb : wf;
  const float* bih = rev ? bih_b : bih_f;
  const float* bhh = rev ? bhh_b : bhh_f;
  f16* gx = rev ? gx_b : gx_f;

  int tid = threadIdx.x;
  int lane = tid & 63, wv = tid >> 6;
  int l16 = lane & 15, l4 = lane >> 4;

  __shared__ __align__(16) f16 embL[64][264];    // +8 pad: 528B row stride
  // fill: 64 m-rows for this block; row r -> emb row of m = blk*64 + r
  for (int r = 0; r < 64; ++r){
    int m = blk*64 + r;
    int t = m >> 5, b = m & 31;
    int tsrc = rev ? (127 - t) : t;
    const int* ix = conv + (size_t)(b*128 + tsrc)*4;
    float s = etbl[(size_t)ix[0]*256 + tid] + etbl[(size_t)ix[1]*256 + tid]
            + etbl[(size_t)ix[2]*256 + tid] + etbl[(size_t)ix[3]*256 + tid];
    embL[r][tid] = (f16)s;
  }
  __syncthreads();

  int mrow = blk*64 + wv*16;
  const f16* arow = &embL[wv*16 + l16][0];
  f16x8 af[8];
#pragma unroll
  for (int kt = 0; kt < 8; ++kt) af[kt] = *(const f16x8*)(arow + kt*32 + l4*8);

  for (int nt = 0; nt < 48; ++nt){
    int n = nt*16 + l16;
    const f16* brow = W16 + (size_t)n*256;   // B[k][n] = Wih[n][k]
    f32x4 acc = {0.f,0.f,0.f,0.f};
#pragma unroll
    for (int kt = 0; kt < 8; ++kt){
      f16x8 bf = *(const f16x8*)(brow + kt*32 + l4*8);
      acc = __builtin_amdgcn_mfma_f32_16x16x32_f16(af[kt], bf, acc, 0, 0, 0);
    }
    float bias = bih[n] + (n < 512 ? bhh[n] : 0.f);
#pragma unroll
    for (int r = 0; r < 4; ++r){
      int m2 = mrow + l4*4 + r;
      gx[(size_t)m2*768 + n] = (f16)(acc[r] + bias);
    }
  }
}

// ---------------------------------------------------------------------------
// K3: GRU (blocks 0-3, proven body) + CONCURRENT bagT gathers (r7 verified:
// 363 us, +16 vs pure GRU; all 4 tables gathered inside the window).
__global__ __launch_bounds__(512, 1) void k_grumega(const f16* __restrict__ gx_f,
                                                    const f16* __restrict__ gx_b,
                                                    const f16* __restrict__ whhf16,
                                                    const f16* __restrict__ whhb16,
                                                    const float* __restrict__ bhh_f,
                                                    const float* __restrict__ bhh_b,
                                                    f16* __restrict__ Abuf,
                                                    const int* __restrict__ src,
                                                    const float* __restrict__ Ct,
                                                    f16* __restrict__ bagT,
                                                    int tab0, int tab1, int tab2, int tab3){
  int bid = blockIdx.x;
  if (bid >= 4){
    int gi = bid - 4;
    int slot = gi >> 6;
    int tab = slot == 0 ? tab0 : slot == 1 ? tab1 : slot == 2 ? tab2 : tab3;
    const float* tbl = Ct + (size_t)tab * 32000 * 256;
    f16* dst = bagT + (size_t)slot * 4194304;       // 16384*256 f16
    int tid = threadIdx.x;
    int d = tid & 255, half = tid >> 8;
    int base = (gi & 63) * 256;
#pragma unroll 2
    for (int it = 0; it < 128; ++it){
      int task = base + it*2 + half;                // b*512 + l
      int4 ix = *(const int4*)(src + (size_t)task*4);
      float s = tbl[(size_t)ix.x*256 + d] + tbl[(size_t)ix.y*256 + d]
              + tbl[(size_t)ix.z*256 + d] + tbl[(size_t)ix.w*256 + d];
      dst[(size_t)task*256 + d] = (f16)s;
    }
    return;
  }

  // ---- GRU block (verbatim proven body) ----
  int dir = bid >> 1, grp = bid & 1, b0 = grp*16;
  const f16*   gx  = dir ? gx_b   : gx_f;
  const f16*   Whh = dir ? whhb16 : whhf16;
  const float* bhh = dir ? bhh_b  : bhh_f;

  int tid = threadIdx.x, lane = tid & 63, wv = tid >> 6;
  int l16 = lane & 15, l4 = lane >> 4;

  __shared__ __align__(16) f16   a16[2][16][264];
  __shared__ __align__(16) float bhnL[256];
  for (int i = tid; i < (16*264*2)/4; i += 512) ((unsigned*)&a16[0][0][0])[i] = 0u;
  if (tid < 256) bhnL[tid] = bhh[512 + tid];

  f16x8 aW[2][3][8];
#pragma unroll
  for (int q = 0; q < 2; ++q){
    int Q = 2*wv + q;
#pragma unroll
    for (int g = 0; g < 3; ++g){
      const f16* wrow = Whh + (size_t)(g*256 + Q*16 + l16)*256;
#pragma unroll
      for (int kt = 0; kt < 8; ++kt) aW[q][g][kt] = *(const f16x8*)(wrow + kt*32 + l4*8);
    }
  }

  const f16* gp = gx + (size_t)(b0 + l16)*768;
  f16* ap  = Abuf + (size_t)(b0 + l16)*128*512 + dir*256 + (size_t)(dir ? 127 : 0)*512;
  int  astep = dir ? -512 : 512;
  f16* app = ap;

  const int d00 = (2*wv    )*16 + l4*4;
  const int d01 = (2*wv + 1)*16 + l4*4;

  f16x4 pend[2];
  pend[0] = (f16x4){(f16)0.f,(f16)0.f,(f16)0.f,(f16)0.f};
  pend[1] = (f16x4){(f16)0.f,(f16)0.f,(f16)0.f,(f16)0.f};

  __syncthreads();

#pragma unroll 1
  for (int t = 0; t < 128; ++t){
    if (t){
      *(f16x4*)(app + d00) = pend[0];
      *(f16x4*)(app + d01) = pend[1];
    }
    f16x4 xg[2][3];
#pragma unroll
    for (int q = 0; q < 2; ++q)
#pragma unroll
      for (int g = 0; g < 3; ++g)
        xg[q][g] = *(const f16x4*)(gp + g*256 + (2*wv+q)*16 + l4*4);

    const f16* rb = &a16[t & 1][l16][l4*8];

    f32x4 accr[2], accz[2];
#pragma unroll
    for (int q = 0; q < 2; ++q){ accr[q] = (f32x4){0.f,0.f,0.f,0.f};
                                 accz[q] = (f32x4){0.f,0.f,0.f,0.f}; }
#pragma unroll
    for (int kt = 0; kt < 8; ++kt){
      f16x8 bf = *(const f16x8*)(rb + kt*32);
#pragma unroll
      for (int q = 0; q < 2; ++q){
        accr[q] = __builtin_amdgcn_mfma_f32_16x16x32_f16(aW[q][0][kt], bf, accr[q], 0, 0, 0);
        accz[q] = __builtin_amdgcn_mfma_f32_16x16x32_f16(aW[q][1][kt], bf, accz[q], 0, 0, 0);
      }
    }
    f32x4 accn[2];
#pragma unroll
    for (int q = 0; q < 2; ++q) accn[q] = (f32x4){0.f,0.f,0.f,0.f};
#pragma unroll
    for (int kt = 0; kt < 8; ++kt){
      f16x8 bf = *(const f16x8*)(rb + kt*32);
#pragma unroll
      for (int q = 0; q < 2; ++q)
        accn[q] = __builtin_amdgcn_mfma_f32_16x16x32_f16(aW[q][2][kt], bf, accn[q], 0, 0, 0);
    }
    float rr[2][4], zz[2][4];
#pragma unroll
    for (int q = 0; q < 2; ++q)
#pragma unroll
      for (int r = 0; r < 4; ++r){
        rr[q][r] = fsig((float)xg[q][0][r] + accr[q][r]);
        zz[q][r] = fsig((float)xg[q][1][r] + accz[q][r]);
      }
    int nxt = (t & 1) ^ 1;
#pragma unroll
    for (int q = 0; q < 2; ++q){
      int d0 = (2*wv+q)*16 + l4*4;
      float4 bh4 = *(const float4*)(&bhnL[d0]);
      f16x4 hold = pend[q];
      f16x4 o4;
#pragma unroll
      for (int r = 0; r < 4; ++r){
        float bh = (r==0)?bh4.x:(r==1)?bh4.y:(r==2)?bh4.z:bh4.w;
        float nn = ftanh((float)xg[q][2][r] + rr[q][r]*(accn[q][r] + bh));
        float h2 = nn + zz[q][r]*((float)hold[r] - nn);
        o4[r] = (f16)h2;
      }
      *(f16x4*)(&a16[nxt][l16][d0]) = o4;
      pend[q] = o4;
    }
    app = ap; ap += astep;
    gp += 24576;
    __syncthreads();
  }
  *(f16x4*)(app + d00) = pend[0];
  *(f16x4*)(app + d01) = pend[1];
}

// ---------------------------------------------------------------------------
// K4: rnnout (0..63) + hidden (64..71) + o-buffer zero (72, replay-safe).
__global__ __launch_bounds__(256) void k_post(const f16* __restrict__ Abuf,
                                              const f16* __restrict__ Ww16,
                                              const float* __restrict__ Wb,
                                              float* __restrict__ rnn,
                                              float* __restrict__ hidden,
                                              float* __restrict__ u,
                                              float* __restrict__ ozero){
  int bid = blockIdx.x;
  int lane = threadIdx.x & 63, wv = threadIdx.x >> 6;
  int l16 = lane & 15, l4 = lane >> 4;
  if (bid == 72){
    for (int i = threadIdx.x; i < 24576; i += 256) ozero[i] = 0.f;
    return;
  }
  if (bid < 64){
    int mrow = bid*64 + wv*16;
    const f16* arow = Abuf + (size_t)(mrow + l16)*512;
    f16x8 af[16];
#pragma unroll
    for (int kt = 0; kt < 16; ++kt) af[kt] = *(const f16x8*)(arow + kt*32 + l4*8);
    for (int nt = 0; nt < 16; ++nt){
      int n = nt*16 + l16;
      const f16* brow = Ww16 + (size_t)n*512;
      f32x4 acc = {0.f,0.f,0.f,0.f};
#pragma unroll
      for (int kt = 0; kt < 16; ++kt){
        f16x8 bf = *(const f16x8*)(brow + kt*32 + l4*8);
        acc = __builtin_amdgcn_mfma_f32_16x16x32_f16(af[kt], bf, acc, 0, 0, 0);
      }
      float bias = Wb[n];
#pragma unroll
      for (int r = 0; r < 4; ++r)
        rnn[(size_t)(mrow + l4*4 + r)*256 + n] = acc[r] + bias;
    }
    return;
  }
  int hb = bid - 64;
  int mt = wv & 1, nt = hb*2 + (wv >> 1);
  int b = mt*16 + l16;
  const f16* rowf = Abuf + ((size_t)b*128 + 127)*512;
  const f16* rowb = Abuf + ((size_t)b*128)*512;
  f16x8 af[16];
#pragma unroll
  for (int kt = 0; kt < 16; ++kt){
    int k = kt*32 + l4*8;
    af[kt] = *(const f16x8*)((k < 256 ? rowf : rowb) + k);
  }
  int n = nt*16 + l16;
  const f16* brow = Ww16 + (size_t)n*512;
  f32x4 acc = {0.f,0.f,0.f,0.f};
#pragma unroll
  for (int kt = 0; kt < 16; ++kt){
    f16x8 bf = *(const f16x8*)(brow + kt*32 + l4*8);
    acc = __builtin_amdgcn_mfma_f32_16x16x32_f16(af[kt], bf, acc, 0, 0, 0);
  }
  float bias = Wb[n];
#pragma unroll
  for (int r = 0; r < 4; ++r){
    int bo = mt*16 + l4*4 + r;
    float v = acc[r] + bias;
    hidden[(size_t)bo*256 + n] = v;
    u[(size_t)bo*256 + n] = v;
  }
}

// ---------------------------------------------------------------------------
// K6: fused hop v2 (r9). 128 blocks = (b<<2)|chunk, 512 threads (8 waves).
// r8 failure root-caused: row-per-thread logit dots = 64-line/instr VMEM
// amplification + only 32 blocks. v2: coalesced wave-dots (lane=4 cols,
// shfl reduce) each wave covering 64 of 512 logits into LDS; 4 chunk-blocks
// per b. u-race (reads vs sibling adds) avoided via per-hop DELTA buffers:
// hop h reads u0+o_{<h}, atomicAdds only o_h (zeroed in k_post).
__global__ __launch_bounds__(512) void k_hop2(const int* __restrict__ kbl,
                                              const int* __restrict__ cvl,
                                              const f16* __restrict__ bagA,
                                              const f16* __restrict__ bagC,
                                              const float* __restrict__ rnn,
                                              const float* __restrict__ u0,
                                              float* __restrict__ o0,
                                              float* __restrict__ o1,
                                              float* __restrict__ o2,
                                              int hop,
                                              float* __restrict__ gp_out){
  int b = blockIdx.x >> 2, c = blockIdx.x & 3;
  int tid = threadIdx.x, lane = tid & 63, wvi = tid >> 6;
  __shared__ float uL[256];
  __shared__ float lgL[512];
  __shared__ float prL[512];
  __shared__ float redm[8], reds[8];
  __shared__ float bcast;
  __shared__ float part[2][256];

  if (tid < 256){
    float v = u0[(size_t)b*256 + tid];
    if (hop >= 1) v += o0[(size_t)b*256 + tid];
    if (hop >= 2) v += o1[(size_t)b*256 + tid];
    uL[tid] = v;
  }
  __syncthreads();

  int kb = kbl[b], cl = cvl[b];
  float4 uv = *(const float4*)(&uL[lane*4]);

  // ---- logits: wave wvi covers l in [wvi*64, wvi*64+64) ----
  for (int i = 0; i < 64; ++i){
    int l = wvi*64 + i;
    f16x4 bv = *(const f16x4*)(bagA + ((size_t)b*512 + l)*256 + lane*4);
    float p0 = (float)bv[0], p1 = (float)bv[1], p2 = (float)bv[2], p3 = (float)bv[3];
    int rel = l - kb;
    if (rel >= 0 && rel < cl){
      int rc = rel < 127 ? rel : 127;
      float4 rv = *(const float4*)(rnn + ((size_t)b*128 + rc)*256 + lane*4);
      p0 += rv.x; p1 += rv.y; p2 += rv.z; p3 += rv.w;
    }
    float p = p0*uv.x + p1*uv.y + p2*uv.z + p3*uv.w;
#pragma unroll
    for (int off = 32; off >= 1; off >>= 1) p += __shfl_down(p, off);
    if (lane == 0) lgL[l] = p;
  }
  __syncthreads();

  if (hop == 2 && c == 0) gp_out[(size_t)b*512 + tid] = fsig(lgL[tid]);

  // ---- softmax over 512 ----
  float v = lgL[tid];
  float m = v;
#pragma unroll
  for (int off = 32; off >= 1; off >>= 1) m = fmaxf(m, __shfl_down(m, off));
  if (lane == 0) redm[wvi] = m;
  __syncthreads();
  if (tid == 0){
    float mm = redm[0];
#pragma unroll
    for (int i = 1; i < 8; ++i) mm = fmaxf(mm, redm[i]);
    bcast = mm;
  }
  __syncthreads();
  float e = __expf(v - bcast);
  float s = e;
#pragma unroll
  for (int off = 32; off >= 1; off >>= 1) s += __shfl_down(s, off);
  if (lane == 0) reds[wvi] = s;
  __syncthreads();
  float stot = reds[0]+reds[1]+reds[2]+reds[3]+reds[4]+reds[5]+reds[6]+reds[7];
  prL[tid] = e * frcp(stot);
  __syncthreads();

  // ---- o_k for this chunk: gl in [c*128, c*128+128), split by hf ----
  int d = tid & 255, hf = tid >> 8;
  float acc = 0.f;
  for (int i = 0; i < 64; ++i){
    int gl = c*128 + hf*64 + i;
    float bag = (float)bagC[((size_t)b*512 + gl)*256 + d];
    int rel = gl - kb;
    if (rel >= 0 && rel < cl){
      int rc = rel < 127 ? rel : 127;
      bag += rnn[((size_t)b*128 + rc)*256 + d];
    }
    acc += prL[gl] * bag;
  }
  part[hf][d] = acc;
  __syncthreads();
  float* oT = hop == 0 ? o0 : hop == 1 ? o1 : o2;
  if (tid < 256) atomicAdd(&oT[(size_t)b*256 + tid], part[0][tid] + part[1][tid]);
}

// ---------------------------------------------------------------------------
// K7 (fused path): encoded from u0 + o0 + o1 + o2.
__global__ void k_encoded2(const float* __restrict__ hidden, const float* __restrict__ u0,
                           const float* __restrict__ o0, const float* __restrict__ o1,
                           const float* __restrict__ o2,
                           const float* __restrict__ pw, const float* __restrict__ pb,
                           float* __restrict__ out){
  int b = blockIdx.x, d = threadIdx.x;
  __shared__ float hL[256], uf[256];
  hL[d] = hidden[(size_t)b*256 + d];
  uf[d] = u0[(size_t)b*256 + d] + o0[(size_t)b*256 + d]
        + o1[(size_t)b*256 + d] + o2[(size_t)b*256 + d];
  __syncthreads();
  const float* w = pw + (size_t)d*512;
  float s = pb[d];
  for (int k = 0; k < 256; ++k) s += hL[k] * w[k];
  for (int k = 0; k < 256; ++k) s += uf[k] * w[256 + k];
  out[(size_t)b*256 + d] = fmaxf(s, 0.f);
}

// ---------------------------------------------------------------------------
// Fallback hop kernels (ntab < 4) — r7 verbatim.
__global__ __launch_bounds__(256) void k_logits(const int* __restrict__ src,
                                                const int* __restrict__ kbl,
                                                const int* __restrict__ cvl,
                                                const float* __restrict__ tblA,
                                                const float* __restrict__ rnn,
                                                const float* __restrict__ u,
                                                float* __restrict__ logits,
                                                const f16* __restrict__ bag){
  int b = blockIdx.x >> 5, chunk = blockIdx.x & 31;
  int lane = threadIdx.x & 63, wv = threadIdx.x >> 6;
  int kb = kbl[b], cl = cvl[b];
  float4 uv = *(const float4*)(u + b*256 + lane*4);
#pragma unroll
  for (int i = 0; i < 4; ++i){
    int l = chunk*16 + wv*4 + i;
    float b0, b1, b2, b3;
    if (bag){
      f16x4 bv = *(const f16x4*)(bag + ((size_t)b*512 + l)*256 + lane*4);
      b0 = (float)bv[0]; b1 = (float)bv[1]; b2 = (float)bv[2]; b3 = (float)bv[3];
    } else {
      const int* sp = src + ((size_t)b*512 + l)*4;
      b0 = b1 = b2 = b3 = 0.f;
#pragma unroll
      for (int m = 0; m < 4; ++m){
        float4 wq = *(const float4*)(tblA + (size_t)sp[m]*256 + lane*4);
        b0 += wq.x; b1 += wq.y; b2 += wq.z; b3 += wq.w;
      }
    }
    int rel = l - kb;
    if (rel >= 0 && rel < cl){
      int rc = rel < 127 ? rel : 127;
      float4 rv = *(const float4*)(rnn + ((size_t)b*128 + rc)*256 + lane*4);
      b0 += rv.x; b1 += rv.y; b2 += rv.z; b3 += rv.w;
    }
    float p = b0*uv.x + b1*uv.y + b2*uv.z + b3*uv.w;
#pragma unroll
    for (int off = 32; off >= 1; off >>= 1) p += __shfl_down(p, off);
    if (lane == 0) logits[(size_t)b*512 + l] = p;
  }
}

__global__ __launch_bounds__(256) void k_okv(const int* __restrict__ src,
                                             const int* __restrict__ kbl,
                                             const int* __restrict__ cvl,
                                             const float* __restrict__ tblC,
                                             const float* __restrict__ rnn,
                                             const float* __restrict__ logits,
                                             float* __restrict__ u,
                                             float* __restrict__ gp_out, int write_gp,
                                             const f16* __restrict__ bagin,
                                             f16* __restrict__ bagout){
  int b = blockIdx.x >> 4, c = blockIdx.x & 15;
  int d = threadIdx.x, lane = d & 63, wv = d >> 6;
  __shared__ float red[4];
  __shared__ float bc;
  __shared__ float pr[512];
  __shared__ int   sidx[128];

  float v0 = logits[(size_t)b*512 + d];
  float v1 = logits[(size_t)b*512 + 256 + d];
  float m = fmaxf(v0, v1);
#pragma unroll
  for (int off = 32; off >= 1; off >>= 1) m = fmaxf(m, __shfl_down(m, off));
  if (lane == 0) red[wv] = m;
  __syncthreads();
  if (d == 0) bc = fmaxf(fmaxf(red[0], red[1]), fmaxf(red[2], red[3]));
  __syncthreads();
  float mx = bc;
  float e0 = __expf(v0 - mx), e1 = __expf(v1 - mx);
  float s = e0 + e1;
#pragma unroll
  for (int off = 32; off >= 1; off >>= 1) s += __shfl_down(s, off);
  __syncthreads();
  if (lane == 0) red[wv] = s;
  __syncthreads();
  if (d == 0) bc = red[0] + red[1] + red[2] + red[3];
  __syncthreads();
  float inv = 1.0f/bc;
  pr[d] = e0*inv; pr[256 + d] = e1*inv;
  if (d < 128) sidx[d] = src[(size_t)b*2048 + c*128 + d];
  if (write_gp && c == 0){
    gp_out[(size_t)b*512 + d]       = fsig(v0);
    gp_out[(size_t)b*512 + 256 + d] = fsig(v1);
  }
  __syncthreads();

  int kb = kbl[b], cl = cvl[b];
  float acc = 0.f;
  for (int l = 0; l < 32; ++l){
    float bag;
    if (bagin){
      bag = (float)bagin[((size_t)b*512 + c*32 + l)*256 + d];
    } else {
      const int* sp = sidx + l*4;
      bag = tblC[(size_t)sp[0]*256 + d] + tblC[(size_t)sp[1]*256 + d]
          + tblC[(size_t)sp[2]*256 + d] + tblC[(size_t)sp[3]*256 + d];
      if (bagout) bagout[((size_t)b*512 + c*32 + l)*256 + d] = (f16)bag;  // RAW
    }
    int rel = (c*32 + l) - kb;
    if (rel >= 0 && rel < cl){
      int rc = rel < 127 ? rel : 127;
      bag += rnn[((size_t)b*128 + rc)*256 + d];
    }
    acc += pr[c*32 + l] * bag;
  }
  atomicAdd(&u[(size_t)b*256 + d], acc);
}

__global__ void k_encoded(const float* __restrict__ hidden, const float* __restrict__ u,
                          const float* __restrict__ pw, const float* __restrict__ pb,
                          float* __restrict__ out){
  int b = blockIdx.x, d = threadIdx.x;
  const float* w = pw + (size_t)d*512;
  float s = pb[d];
  for (int k = 0; k < 256; ++k) s += hidden[b*256 + k] * w[k];
  for (int k = 0; k < 256; ++k) s += u[b*256 + k]      * w[256 + k];
  out[(size_t)b*256 + d] = fmaxf(s, 0.f);
}

// ---------------------------------------------------------------------------
extern "C" void kernel_launch(void* const* d_in, const int* in_sizes, int n_in,
                              void* d_out, int out_size, void* d_ws, size_t ws_size,
                              hipStream_t stream){
  (void)in_sizes; (void)n_in; (void)out_size;
  float* out = (float*)d_out;  // [0:16384) global_pointer, [16384:24576) encoded

  const size_t WS_NEEDED = 25034752;
  if (ws_size < WS_NEEDED){
    k_zero<<<96, 256, 0, stream>>>(out);
    return;
  }

  const int* conv  = (const int*)d_in[0];
  const int* src   = (const int*)d_in[1];
  const int* kbl   = (const int*)d_in[2];
  const int* cvl   = (const int*)d_in[3];
  const float* emb_ctx = (const float*)d_in[4];
  const float* Ct      = (const float*)d_in[5];
  const float* Wih_f = (const float*)d_in[6];
  const float* Whh_f = (const float*)d_in[7];
  const float* bih_f = (const float*)d_in[8];
  const float* bhh_f = (const float*)d_in[9];
  const float* Wih_b = (const float*)d_in[10];
  const float* Whh_b = (const float*)d_in[11];
  const float* bih_b = (const float*)d_in[12];
  const float* bhh_b = (const float*)d_in[13];
  const float* Ww = (const float*)d_in[14];
  const float* Wb = (const float*)d_in[15];
  const float* pw = (const float*)d_in[16];
  const float* pb = (const float*)d_in[17];

  char* ws = (char*)d_ws;
  // emb region [0, 2MB) is dead in r9 (embbag folded into gx2) -> o-buffers.
  float* o0    = (float*)(ws);                 //  32,768
  float* o1    = (float*)(ws + 32768);         //  32,768
  float* o2    = (float*)(ws + 65536);         //  32,768
  f16*   gx_f   = (f16*)(ws + 2097152);        //  6,291,456  [t*32+b][768] f16
  f16*   gx_b   = (f16*)(ws + 8388608);        //  6,291,456
  f16*   Abuf   = (f16*)(ws + 14680064);       //  4,194,304  [b*128+t][512] f16
  float* rnn    = (float*)(ws + 18874368);     //  4,194,304  [b*128+t][256] f32
  float* hidden = (float*)(ws + 23068672);     //     32,768
  float* u      = (float*)(ws + 23101440);     //     32,768
  float* logits = (float*)(ws + 23134208);     //     65,536
  f16*   wihf16 = (f16*)(ws + 23199744);       //    393,216  [768][256]
  f16*   wihb16 = (f16*)(ws + 23592960);       //    393,216
  f16*   whhf16 = (f16*)(ws + 23986176);       //    393,216
  f16*   whhb16 = (f16*)(ws + 24379392);       //    393,216
  f16*   ww16   = (f16*)(ws + 24772608);       //    262,144  [256][512]
                                               // end 25,034,752
  f16*   bagbuf = (f16*)(ws + 2097152);        // fallback raw-bag (gx region)
  f16*   bagT   = (f16*)(ws + WS_NEEDED);
  size_t avail  = ws_size - WS_NEEDED;
  int ntab = (int)(avail / 8388608); if (ntab > 4) ntab = 4;
  const int tabids[4] = {1, 2, 3, 0};
  const f16* bt[4] = {nullptr, nullptr, nullptr, nullptr};
  for (int s = 0; s < ntab; ++s) bt[tabids[s]] = bagT + (size_t)s*4194304;

  k_prep<<<768, 256, 0, stream>>>(Wih_f, Wih_b, Whh_f, Whh_b, Ww,
                                  wihf16, wihb16, whhf16, whhb16, ww16);
  k_gx2<<<128, 256, 0, stream>>>(conv, emb_ctx, wihf16, wihb16,
                                 bih_f, bhh_f, bih_b, bhh_b, gx_f, gx_b);
  k_grumega<<<4 + 64*ntab, 512, 0, stream>>>(gx_f, gx_b, whhf16, whhb16,
                                             bhh_f, bhh_b, Abuf,
                                             src, Ct, bagT,
                                             tabids[0], tabids[1], tabids[2], tabids[3]);
  k_post<<<73, 256, 0, stream>>>(Abuf, ww16, Wb, rnn, hidden, u, o0);

  if (ntab == 4){
    for (int hop = 0; hop < 3; ++hop)
      k_hop2<<<128, 512, 0, stream>>>(kbl, cvl, bt[hop], bt[hop+1], rnn,
                                      u, o0, o1, o2, hop, out);
    k_encoded2<<<32, 256, 0, stream>>>(hidden, u, o0, o1, o2, pw, pb, out + 16384);
  } else {
    for (int hop = 0; hop < 3; ++hop){
      const float* tA = Ct + (size_t)hop     * 32000 * 256;
      const float* tC = Ct + (size_t)(hop+1) * 32000 * 256;
      const f16* lbag = bt[hop] ? bt[hop] : (hop ? bagbuf : (const f16*)nullptr);
      const f16* obag = bt[hop + 1];
      f16* obout = (!obag && hop < 2) ? bagbuf : (f16*)nullptr;
      k_logits<<<1024, 256, 0, stream>>>(src, kbl, cvl, tA, rnn, u, logits, lbag);
      k_okv<<<512, 256, 0, stream>>>(src, kbl, cvl, tC, rnn, logits, u,
                                     out, hop == 2 ? 1 : 0, obag, obout);
    }
    k_encoded<<<32, 256, 0, stream>>>(hidden, u, pw, pb, out + 16384);
  }
}